// Round 2
// baseline (263.539 us; speedup 1.0000x reference)
//
#include <hip/hip_runtime.h>
#include <stdint.h>

#define B_ 8
#define S_ 1024
#define DM_ 1024
#define H_ 16
#define DH_ 64
#define M_ (B_*S_)

typedef unsigned short u16;
typedef unsigned int u32;
typedef __attribute__((ext_vector_type(8))) short bf16x8;
typedef __attribute__((ext_vector_type(4))) float f32x4;

__device__ __forceinline__ u16 f2bf(float f){
  union { float f; u32 u; } x; x.f = f;
  u32 r = x.u + 0x7fffu + ((x.u >> 16) & 1u);
  return (u16)(r >> 16);
}
__device__ __forceinline__ float bf2f(u16 u){
  union { u32 u; float f; } x; x.u = ((u32)u) << 16; return x.f;
}
__device__ __forceinline__ void gload16(const void* g, void* l){
  __builtin_amdgcn_global_load_lds((const __attribute__((address_space(1))) void*)g,
                                   (__attribute__((address_space(3))) void*)l, 16, 0, 0);
}

// ---------------- convert activations fp32 -> bf16 ----------------
__global__ void k_cvt_act(const float* __restrict__ v, const float* __restrict__ k,
                          const float* __restrict__ q, u16* __restrict__ vb,
                          u16* __restrict__ kb, u16* __restrict__ qb){
  int z = blockIdx.y;
  const float* src = (z == 0) ? v : (z == 1) ? k : q;
  u16* dst = (z == 0) ? vb : (z == 1) ? kb : qb;
  size_t i = ((size_t)blockIdx.x * blockDim.x + threadIdx.x) * 8;
  float4 a = *(const float4*)(src + i);
  float4 b = *(const float4*)(src + i + 4);
  uint4 o;
  o.x = (u32)f2bf(a.x) | ((u32)f2bf(a.y) << 16);
  o.y = (u32)f2bf(a.z) | ((u32)f2bf(a.w) << 16);
  o.z = (u32)f2bf(b.x) | ((u32)f2bf(b.y) << 16);
  o.w = (u32)f2bf(b.z) | ((u32)f2bf(b.w) << 16);
  *(uint4*)(dst + i) = o;
}

// ---------------- convert + transpose weights fp32[K][N] -> bf16[N][K] ----------------
__global__ void k_cvt_wt(const float* __restrict__ w0, const float* __restrict__ w1,
                         const float* __restrict__ w2, const float* __restrict__ w3,
                         const float* __restrict__ w4,
                         u16* __restrict__ t0, u16* __restrict__ t1, u16* __restrict__ t2,
                         u16* __restrict__ t3, u16* __restrict__ t4){
  __shared__ float tile[32][33];
  int z = blockIdx.z;
  const float* src = (z==0)?w0:(z==1)?w1:(z==2)?w2:(z==3)?w3:w4;
  u16* dst = (z==0)?t0:(z==1)?t1:(z==2)?t2:(z==3)?t3:t4;
  int n0 = blockIdx.x * 32, k0 = blockIdx.y * 32;
  int tx = threadIdx.x, ty = threadIdx.y;
#pragma unroll
  for (int i=0;i<4;i++) tile[ty+8*i][tx] = src[(size_t)(k0+ty+8*i)*DM_ + n0+tx];
  __syncthreads();
#pragma unroll
  for (int i=0;i<4;i++) dst[(size_t)(n0+ty+8*i)*DM_ + k0+tx] = f2bf(tile[tx][ty+8*i]);
}

// ---------------- 128x128 BK=64 bf16 MFMA GEMM:  Out[M][1024] = A[M][1024] @ Bt[N][K]^T + bias ----------------
template<int OUTF32>
__global__ __launch_bounds__(256) void k_gemm(const u16* __restrict__ A, const u16* __restrict__ Bt,
                                              const float* __restrict__ bias, void* __restrict__ Out){
  __shared__ u16 As[128*64];
  __shared__ u16 Bs[128*64];
  const int tid = threadIdx.x;
  const int w = tid >> 6, l = tid & 63, g = l >> 4, s = l & 15;
  const int wr = w >> 1, wc = w & 1;
  const int m0 = blockIdx.x << 7, n0 = blockIdx.y << 7;
  f32x4 acc[4][4];
#pragma unroll
  for (int i=0;i<4;i++)
#pragma unroll
    for (int j=0;j<4;j++) acc[i][j] = (f32x4){0.f,0.f,0.f,0.f};

  for (int k0 = 0; k0 < 1024; k0 += 64){
    __syncthreads();
#pragma unroll
    for (int i=0;i<4;i++){
      int c = tid + i*256;
      int m = c >> 3, slot = c & 7;
      gload16(A + ((size_t)(m0+m) << 10) + (k0 + ((slot ^ (m & 7)) << 3)),
              &As[(i*256 + w*64) * 8]);
    }
#pragma unroll
    for (int i=0;i<4;i++){
      int c = tid + i*256;
      int n = c >> 3, slot = c & 7;
      gload16(Bt + ((size_t)(n0+n) << 10) + (k0 + ((slot ^ (n & 7)) << 3)),
              &Bs[(i*256 + w*64) * 8]);
    }
    __syncthreads();
#pragma unroll
    for (int ks=0; ks<2; ks++){
      bf16x8 af[4], bfv[4];
#pragma unroll
      for (int mi=0;mi<4;mi++){
        int m = wr*64 + mi*16 + s;
        af[mi] = *(const bf16x8*)&As[m*64 + (((ks*4+g) ^ (s & 7)) << 3)];
      }
#pragma unroll
      for (int ni=0;ni<4;ni++){
        int n = wc*64 + ni*16 + s;
        bfv[ni] = *(const bf16x8*)&Bs[n*64 + (((ks*4+g) ^ (s & 7)) << 3)];
      }
#pragma unroll
      for (int mi=0;mi<4;mi++)
#pragma unroll
        for (int ni=0;ni<4;ni++)
          acc[mi][ni] = __builtin_amdgcn_mfma_f32_16x16x32_bf16(af[mi], bfv[ni], acc[mi][ni], 0, 0, 0);
    }
  }
#pragma unroll
  for (int ni=0;ni<4;ni++){
    int col = n0 + wc*64 + ni*16 + s;
    float bv = bias[col];
#pragma unroll
    for (int mi=0;mi<4;mi++){
      int row = m0 + wr*64 + mi*16 + g*4;
#pragma unroll
      for (int r=0;r<4;r++){
        float val = acc[mi][ni][r] + bv;
        if (OUTF32)
          ((float*)Out)[((size_t)(row+r) << 10) + col] = val;
        else
          ((u16*)Out)[((size_t)(row+r) << 10) + col] = f2bf(val);
      }
    }
  }
}

// ---------------- flash attention + R-gating ----------------
// grid: (S/64, B*H). block 256. Each wave owns 16 q-rows.
__global__ __launch_bounds__(256) void k_attn(const u16* __restrict__ qp, const u16* __restrict__ kp,
                                              const u16* __restrict__ vp, const u16* __restrict__ rp,
                                              u16* __restrict__ gated){
  __shared__ u16 Ks[64*64];        // [sj][d] row-major, k-slot XOR-swizzled
  __shared__ u16 Vt[64*64];        // [d][j] transposed, j-slot XOR-swizzled: slot=(j>>3)^(d&7)
  __shared__ u16 Ps[4][8*16*8];    // per-wave P in A-frag order [jblk][si][jj]
  const int tid = threadIdx.x;
  const int w = tid >> 6, l = tid & 63, g = l >> 4, s = l & 15;
  const int q0 = blockIdx.x << 6;
  const int bh = blockIdx.y;
  const int b = bh >> 4, h = bh & 15;
  const size_t base = ((size_t)b << 20);   // b * S * 1024
  const int colh = h << 6;
  const float KL = 1.4426950408889634f / 32.0f;  // log2(e)/SCALE, SCALE=32

  const size_t qoff = base + ((size_t)(q0 + w*16 + s) << 10) + colh;
  bf16x8 qf0 = *(const bf16x8*)(qp + qoff + g*8);
  bf16x8 qf1 = *(const bf16x8*)(qp + qoff + 32 + g*8);

  float mrun[4], lsum[4];
  f32x4 of[4];
#pragma unroll
  for (int r=0;r<4;r++){ mrun[r] = -1e30f; lsum[r] = 0.f; }
#pragma unroll
  for (int d=0;d<4;d++) of[d] = (f32x4){0.f,0.f,0.f,0.f};

  for (int kv0 = 0; kv0 < S_; kv0 += 64){
    __syncthreads();
    // K: global_load_lds, swizzled source (involution: slot ^ (row&7))
#pragma unroll
    for (int i=0;i<2;i++){
      int c = tid + i*256;
      int sj = c >> 3, slot = c & 7;
      gload16(kp + base + ((size_t)(kv0+sj) << 10) + colh + ((slot ^ (sj & 7)) << 3),
              &Ks[(i*256 + w*64) * 8]);
    }
    // V: reg-staged TRANSPOSE into Vt[d][j]; lane=j, wave=d-block (write conflict-free)
    {
      const u16* vsrc = vp + base + ((size_t)(kv0 + l) << 10) + colh + w*16;
      bf16x8 va = *(const bf16x8*)(vsrc);
      bf16x8 vb2 = *(const bf16x8*)(vsrc + 8);
#pragma unroll
      for (int i=0;i<8;i++){
        int d = w*16 + i;
        Vt[d*64 + (((l>>3) ^ (d&7)) << 3) + (l&7)] = (u16)va[i];
      }
#pragma unroll
      for (int i=0;i<8;i++){
        int d = w*16 + 8 + i;
        Vt[d*64 + (((l>>3) ^ (d&7)) << 3) + (l&7)] = (u16)vb2[i];
      }
    }
    __syncthreads();

    // energy E[si][sj] via MFMA (A=Q regs, B=K from LDS)
    f32x4 e[4];
#pragma unroll
    for (int sjf=0;sjf<4;sjf++){
      e[sjf] = (f32x4){0.f,0.f,0.f,0.f};
      int sj = sjf*16 + s;
      bf16x8 kf0 = *(const bf16x8*)&Ks[sj*64 + (((0*4+g) ^ (s & 7)) << 3)];
      e[sjf] = __builtin_amdgcn_mfma_f32_16x16x32_bf16(qf0, kf0, e[sjf], 0, 0, 0);
      bf16x8 kf1 = *(const bf16x8*)&Ks[sj*64 + (((1*4+g) ^ (s & 7)) << 3)];
      e[sjf] = __builtin_amdgcn_mfma_f32_16x16x32_bf16(qf1, kf1, e[sjf], 0, 0, 0);
    }
    // online softmax (rows si = g*4 + r)
    float rm[4];
#pragma unroll
    for (int r=0;r<4;r++)
      rm[r] = fmaxf(fmaxf(e[0][r], e[1][r]), fmaxf(e[2][r], e[3][r]));
#pragma unroll
    for (int off=1; off<16; off<<=1)
#pragma unroll
      for (int r=0;r<4;r++)
        rm[r] = fmaxf(rm[r], __shfl_xor(rm[r], off, 64));
    float al[4];
#pragma unroll
    for (int r=0;r<4;r++){
      float nm = fmaxf(mrun[r], rm[r]);
      al[r] = exp2f((mrun[r] - nm) * KL);
      mrun[r] = nm;
      lsum[r] *= al[r];
    }
#pragma unroll
    for (int d=0; d<4; d++)
#pragma unroll
      for (int r=0;r<4;r++) of[d][r] *= al[r];
#pragma unroll
    for (int sjf=0;sjf<4;sjf++){
      int sj = sjf*16 + s;
#pragma unroll
      for (int r=0;r<4;r++){
        float p = exp2f((e[sjf][r] - mrun[r]) * KL);
        lsum[r] += p;
        Ps[w][((sj >> 3)*16 + g*4 + r)*8 + (sj & 7)] = f2bf(p);
      }
    }
    // PV: A = P (from per-wave LDS), B = Vt rows (plain bf16x8 reads, same pattern as K)
    bf16x8 pa0 = *(const bf16x8*)&Ps[w][(g*16 + s)*8];
    bf16x8 pa1 = *(const bf16x8*)&Ps[w][((4+g)*16 + s)*8];
#pragma unroll
    for (int df=0; df<4; df++){
      int d = df*16 + s;
      bf16x8 v0 = *(const bf16x8*)&Vt[d*64 + ((g ^ (s & 7)) << 3)];
      bf16x8 v1 = *(const bf16x8*)&Vt[d*64 + (((4+g) ^ (s & 7)) << 3)];
      of[df] = __builtin_amdgcn_mfma_f32_16x16x32_bf16(pa0, v0, of[df], 0, 0, 0);
      of[df] = __builtin_amdgcn_mfma_f32_16x16x32_bf16(pa1, v1, of[df], 0, 0, 0);
    }
  }
  // epilogue: normalize, gate with R, store bf16
  float inv[4];
#pragma unroll
  for (int r=0;r<4;r++){
    float t = lsum[r];
#pragma unroll
    for (int off=1; off<16; off<<=1) t += __shfl_xor(t, off, 64);
    inv[r] = 1.0f / t;
  }
#pragma unroll
  for (int df=0; df<4; df++){
#pragma unroll
    for (int r=0;r<4;r++){
      size_t row = (size_t)(q0 + w*16 + g*4 + r);
      size_t idx = base + (row << 10) + colh + df*16 + s;
      float o = of[df][r] * inv[r];
      float rg = bf2f(rp[idx]);
      gated[idx] = f2bf(o * rg);
    }
  }
}

extern "C" void kernel_launch(void* const* d_in, const int* in_sizes, int n_in,
                              void* d_out, int out_size, void* d_ws, size_t ws_size,
                              hipStream_t stream){
  (void)in_sizes; (void)n_in; (void)out_size; (void)ws_size;
  const float* value = (const float*)d_in[0];
  const float* key   = (const float*)d_in[1];
  const float* query = (const float*)d_in[2];
  const float* Wq = (const float*)d_in[3];  const float* bq = (const float*)d_in[4];
  const float* Wk = (const float*)d_in[5];  const float* bk = (const float*)d_in[6];
  const float* Wv = (const float*)d_in[7];  const float* bv = (const float*)d_in[8];
  const float* Wr = (const float*)d_in[9];  const float* br = (const float*)d_in[10];
  const float* Wo = (const float*)d_in[11]; const float* bo = (const float*)d_in[12];

  char* ws = (char*)d_ws;
  const size_t MB = (size_t)1 << 20;
  u16* qb  = (u16*)(ws + 0*MB);      // 16 MB each (bf16 activations)
  u16* kb  = (u16*)(ws + 16*MB);
  u16* vb  = (u16*)(ws + 32*MB);
  u16* wqt = (u16*)(ws + 48*MB);     // 2 MB each (bf16 transposed weights)
  u16* wkt = (u16*)(ws + 50*MB);
  u16* wvt = (u16*)(ws + 52*MB);
  u16* wrt = (u16*)(ws + 54*MB);
  u16* wot = (u16*)(ws + 56*MB);
  u16* qpj = (u16*)(ws + 58*MB);     // 16 MB each (bf16 projections)
  u16* kpj = (u16*)(ws + 74*MB);
  u16* vpj = (u16*)(ws + 90*MB);
  u16* rpj = (u16*)(ws + 106*MB);
  u16* gat = qb;                     // alias: qb dead after projections

  k_cvt_act<<<dim3(4096, 3), 256, 0, stream>>>(value, key, query, vb, kb, qb);
  k_cvt_wt<<<dim3(32, 32, 5), dim3(32, 8), 0, stream>>>(Wq, Wk, Wv, Wr, Wo,
                                                        wqt, wkt, wvt, wrt, wot);
  k_gemm<0><<<dim3(64, 8), 256, 0, stream>>>(qb, wqt, bq, qpj);
  k_gemm<0><<<dim3(64, 8), 256, 0, stream>>>(qb, wrt, br, rpj);
  k_gemm<0><<<dim3(64, 8), 256, 0, stream>>>(kb, wkt, bk, kpj);
  k_gemm<0><<<dim3(64, 8), 256, 0, stream>>>(vb, wvt, bv, vpj);
  k_attn<<<dim3(16, 128), 256, 0, stream>>>(qpj, kpj, vpj, rpj, gat);
  k_gemm<1><<<dim3(64, 8), 256, 0, stream>>>(gat, wot, bo, d_out);
}

// Round 3
// 224.087 us; speedup vs baseline: 1.1761x; 1.1761x over previous
//
#include <hip/hip_runtime.h>
#include <stdint.h>

#define B_ 8
#define S_ 1024
#define DM_ 1024
#define H_ 16
#define DH_ 64
#define M_ (B_*S_)

typedef unsigned short u16;
typedef unsigned int u32;
typedef __attribute__((ext_vector_type(8))) short bf16x8;
typedef __attribute__((ext_vector_type(4))) float f32x4;

__device__ __forceinline__ u16 f2bf(float f){
  union { float f; u32 u; } x; x.f = f;
  u32 r = x.u + 0x7fffu + ((x.u >> 16) & 1u);
  return (u16)(r >> 16);
}
__device__ __forceinline__ float bf2f(u16 u){
  union { u32 u; float f; } x; x.u = ((u32)u) << 16; return x.f;
}
__device__ __forceinline__ u32 cvtpk(float lo, float hi){
  u32 r; asm("v_cvt_pk_bf16_f32 %0, %1, %2" : "=v"(r) : "v"(lo), "v"(hi)); return r;
}
__device__ __forceinline__ void gload16(const void* g, void* l){
  __builtin_amdgcn_global_load_lds((const __attribute__((address_space(1))) void*)g,
                                   (__attribute__((address_space(3))) void*)l, 16, 0, 0);
}

// ---------------- convert activations fp32 -> bf16 ----------------
__global__ void k_cvt_act(const float* __restrict__ v, const float* __restrict__ k,
                          const float* __restrict__ q, u16* __restrict__ vb,
                          u16* __restrict__ kb, u16* __restrict__ qb){
  int z = blockIdx.y;
  const float* src = (z == 0) ? v : (z == 1) ? k : q;
  u16* dst = (z == 0) ? vb : (z == 1) ? kb : qb;
  size_t i = ((size_t)blockIdx.x * blockDim.x + threadIdx.x) * 8;
  float4 a = *(const float4*)(src + i);
  float4 b = *(const float4*)(src + i + 4);
  uint4 o;
  o.x = (u32)f2bf(a.x) | ((u32)f2bf(a.y) << 16);
  o.y = (u32)f2bf(a.z) | ((u32)f2bf(a.w) << 16);
  o.z = (u32)f2bf(b.x) | ((u32)f2bf(b.y) << 16);
  o.w = (u32)f2bf(b.z) | ((u32)f2bf(b.w) << 16);
  *(uint4*)(dst + i) = o;
}

// ---------------- convert + transpose weights fp32[K][N] -> bf16[N][K] ----------------
__global__ void k_cvt_wt(const float* __restrict__ w0, const float* __restrict__ w1,
                         const float* __restrict__ w2, const float* __restrict__ w3,
                         const float* __restrict__ w4,
                         u16* __restrict__ t0, u16* __restrict__ t1, u16* __restrict__ t2,
                         u16* __restrict__ t3, u16* __restrict__ t4){
  __shared__ float tile[32][33];
  int z = blockIdx.z;
  const float* src = (z==0)?w0:(z==1)?w1:(z==2)?w2:(z==3)?w3:w4;
  u16* dst = (z==0)?t0:(z==1)?t1:(z==2)?t2:(z==3)?t3:t4;
  int n0 = blockIdx.x * 32, k0 = blockIdx.y * 32;
  int tx = threadIdx.x, ty = threadIdx.y;
#pragma unroll
  for (int i=0;i<4;i++) tile[ty+8*i][tx] = src[(size_t)(k0+ty+8*i)*DM_ + n0+tx];
  __syncthreads();
#pragma unroll
  for (int i=0;i<4;i++) dst[(size_t)(n0+ty+8*i)*DM_ + k0+tx] = f2bf(tile[tx][ty+8*i]);
}

// ---------------- 128x128 BK=64 bf16 MFMA GEMM:  Out[M][1024] = A[M][1024] @ Bt[N][K]^T + bias ----
// OUTMODE 0: bf16 [row][col]; 1: f32 [row][col]; 2: bf16 V-transposed [(b*16+h)*64+d][sq]
template<int OUTMODE>
__global__ __launch_bounds__(256) void k_gemm(const u16* __restrict__ A, const u16* __restrict__ Bt,
                                              const float* __restrict__ bias, void* __restrict__ Out){
  __shared__ u16 As[128*64];
  __shared__ u16 Bs[128*64];
  const int tid = threadIdx.x;
  const int w = tid >> 6, l = tid & 63, g = l >> 4, s = l & 15;
  const int wr = w >> 1, wc = w & 1;
  const int m0 = blockIdx.x << 7, n0 = blockIdx.y << 7;
  f32x4 acc[4][4];
#pragma unroll
  for (int i=0;i<4;i++)
#pragma unroll
    for (int j=0;j<4;j++) acc[i][j] = (f32x4){0.f,0.f,0.f,0.f};

  for (int k0 = 0; k0 < 1024; k0 += 64){
    __syncthreads();
#pragma unroll
    for (int i=0;i<4;i++){
      int c = tid + i*256;
      int m = c >> 3, slot = c & 7;
      gload16(A + ((size_t)(m0+m) << 10) + (k0 + ((slot ^ (m & 7)) << 3)),
              &As[(i*256 + w*64) * 8]);
    }
#pragma unroll
    for (int i=0;i<4;i++){
      int c = tid + i*256;
      int n = c >> 3, slot = c & 7;
      gload16(Bt + ((size_t)(n0+n) << 10) + (k0 + ((slot ^ (n & 7)) << 3)),
              &Bs[(i*256 + w*64) * 8]);
    }
    __syncthreads();
#pragma unroll
    for (int ks=0; ks<2; ks++){
      bf16x8 af[4], bfv[4];
#pragma unroll
      for (int mi=0;mi<4;mi++){
        int m = wr*64 + mi*16 + s;
        af[mi] = *(const bf16x8*)&As[m*64 + (((ks*4+g) ^ (s & 7)) << 3)];
      }
#pragma unroll
      for (int ni=0;ni<4;ni++){
        int n = wc*64 + ni*16 + s;
        bfv[ni] = *(const bf16x8*)&Bs[n*64 + (((ks*4+g) ^ (s & 7)) << 3)];
      }
#pragma unroll
      for (int mi=0;mi<4;mi++)
#pragma unroll
        for (int ni=0;ni<4;ni++)
          acc[mi][ni] = __builtin_amdgcn_mfma_f32_16x16x32_bf16(af[mi], bfv[ni], acc[mi][ni], 0, 0, 0);
    }
  }
#pragma unroll
  for (int ni=0;ni<4;ni++){
    int col = n0 + wc*64 + ni*16 + s;
    float bv = bias[col];
#pragma unroll
    for (int mi=0;mi<4;mi++){
      int row = m0 + wr*64 + mi*16 + g*4;
      if (OUTMODE == 2){
        // V-transposed: Vt[(b*16+h)*64 + d][sq], 4 contiguous sq per lane -> packed 8B store
        union { short4 v; u16 e[4]; } pk;
#pragma unroll
        for (int r=0;r<4;r++) pk.e[r] = f2bf(acc[mi][ni][r] + bv);
        size_t vrow = ((size_t)(row >> 10) * 16 + (col >> 6)) * 64 + (col & 63);
        *(short4*)&((u16*)Out)[(vrow << 10) + (row & 1023)] = pk.v;
      } else {
#pragma unroll
        for (int r=0;r<4;r++){
          float val = acc[mi][ni][r] + bv;
          if (OUTMODE == 1)
            ((float*)Out)[((size_t)(row+r) << 10) + col] = val;
          else
            ((u16*)Out)[((size_t)(row+r) << 10) + col] = f2bf(val);
        }
      }
    }
  }
}

// ---------------- flash attention + R-gating (swapped QK^T, packed P) ----------------
// grid: (S/64, B*H). block 256. Each wave owns 16 q-rows.
__global__ __launch_bounds__(256) void k_attn(const u16* __restrict__ qp, const u16* __restrict__ kp,
                                              const u16* __restrict__ vtg, const u16* __restrict__ rp,
                                              u16* __restrict__ gated){
  __shared__ u16 Ks[64*64];        // [sj][d], k-slot XOR-swizzled (involution slot^(sj&7))
  __shared__ u16 Vs[64*64];        // [d][sj], sj-slot XOR-swizzled (involution slot^(d&7))
  __shared__ u32 PsU[4*16*32];     // per-wave P, rows si=s, 32 u32 (64 bf16) per row, XOR-banked
  const int tid = threadIdx.x;
  const int w = tid >> 6, l = tid & 63, g = l >> 4, s = l & 15;
  const int q0 = blockIdx.x << 6;
  const int bh = blockIdx.y;
  const int b = bh >> 4, h = bh & 15;
  const size_t base = ((size_t)b << 20);          // b * S * DM
  const int colh = h << 6;
  const float KL = 1.4426950408889634f / 32.0f;   // log2(e)/SCALE, SCALE=32

  const size_t qoff = base + ((size_t)(q0 + w*16 + s) << 10) + colh;
  bf16x8 qf0 = *(const bf16x8*)(qp + qoff + g*8);
  bf16x8 qf1 = *(const bf16x8*)(qp + qoff + 32 + g*8);
  const size_t vbase = ((size_t)(b*16 + h)) << 16;   // (b*16+h)*64*1024 u16

  u32* PsW = PsU + (w << 9);
  const int sx2 = (s & 15) << 1;

  float mrun = -1e30f, lsum = 0.f;
  f32x4 of[4];
#pragma unroll
  for (int d=0;d<4;d++) of[d] = (f32x4){0.f,0.f,0.f,0.f};

  for (int kv0 = 0; kv0 < S_; kv0 += 64){
    __syncthreads();
    // stage K tile [sj][d]
#pragma unroll
    for (int i=0;i<2;i++){
      int c = tid + i*256;
      int sj = c >> 3, slot = c & 7;
      gload16(kp + base + ((size_t)(kv0+sj) << 10) + colh + ((slot ^ (sj & 7)) << 3),
              &Ks[(i*256 + w*64) * 8]);
    }
    // stage Vt tile [d][sj] (V pre-transposed globally)
#pragma unroll
    for (int i=0;i<2;i++){
      int c = tid + i*256;
      int d = c >> 3, slot = c & 7;
      gload16(vtg + vbase + ((size_t)d << 10) + kv0 + ((slot ^ (d & 7)) << 3),
              &Vs[(i*256 + w*64) * 8]);
    }
    __syncthreads();

    // swapped QK^T: e2 = mfma(K, Q) -> lane (g,s) holds E[sj=16*sjf+4g+r][si=s]
    f32x4 e2[4];
#pragma unroll
    for (int sjf=0;sjf<4;sjf++){
      e2[sjf] = (f32x4){0.f,0.f,0.f,0.f};
      int sj = sjf*16 + s;
      bf16x8 kf0 = *(const bf16x8*)&Ks[sj*64 + ((g ^ (s & 7)) << 3)];
      e2[sjf] = __builtin_amdgcn_mfma_f32_16x16x32_bf16(kf0, qf0, e2[sjf], 0, 0, 0);
      bf16x8 kf1 = *(const bf16x8*)&Ks[sj*64 + (((4+g) ^ (s & 7)) << 3)];
      e2[sjf] = __builtin_amdgcn_mfma_f32_16x16x32_bf16(kf1, qf1, e2[sjf], 0, 0, 0);
    }
    // online softmax: whole row si=s is local (16 vals) + 4 g-lanes
    float rm = fmaxf(fmaxf(fmaxf(e2[0][0], e2[0][1]), fmaxf(e2[0][2], e2[0][3])),
                     fmaxf(fmaxf(e2[1][0], e2[1][1]), fmaxf(e2[1][2], e2[1][3])));
    rm = fmaxf(rm, fmaxf(fmaxf(fmaxf(e2[2][0], e2[2][1]), fmaxf(e2[2][2], e2[2][3])),
                         fmaxf(fmaxf(e2[3][0], e2[3][1]), fmaxf(e2[3][2], e2[3][3]))));
    rm = fmaxf(rm, __shfl_xor(rm, 16, 64));
    rm = fmaxf(rm, __shfl_xor(rm, 32, 64));
    float nm = fmaxf(mrun, rm);
    float alpha = __builtin_amdgcn_exp2f((mrun - nm) * KL);
    mrun = nm;
    lsum *= alpha;
    float ac[4];
#pragma unroll
    for (int r=0;r<4;r++) ac[r] = __shfl(alpha, g*4 + r, 64);
#pragma unroll
    for (int d=0; d<4; d++)
#pragma unroll
      for (int r=0;r<4;r++) of[d][r] *= ac[r];

    const float mk = mrun * KL;
#pragma unroll
    for (int sjf=0;sjf<4;sjf++){
      float p0 = __builtin_amdgcn_exp2f(e2[sjf][0]*KL - mk);
      float p1 = __builtin_amdgcn_exp2f(e2[sjf][1]*KL - mk);
      float p2 = __builtin_amdgcn_exp2f(e2[sjf][2]*KL - mk);
      float p3 = __builtin_amdgcn_exp2f(e2[sjf][3]*KL - mk);
      lsum += (p0 + p1) + (p2 + p3);
      uint2 pk; pk.x = cvtpk(p0, p1); pk.y = cvtpk(p2, p3);
      int phys = (8*sjf + 2*g) ^ sx2;
      *reinterpret_cast<uint2*>(&PsW[(s << 5) + phys]) = pk;
    }
    // gather A-frag P: logical u32 slots {4g+w} and {16+4g+w}
    union { u32 u[4]; bf16x8 v; } pa0, pa1;
    {
      uint2 r0 = *reinterpret_cast<const uint2*>(&PsW[(s << 5) + ((4*g    ) ^ sx2)]);
      uint2 r1 = *reinterpret_cast<const uint2*>(&PsW[(s << 5) + ((4*g + 2) ^ sx2)]);
      pa0.u[0] = r0.x; pa0.u[1] = r0.y; pa0.u[2] = r1.x; pa0.u[3] = r1.y;
      uint2 r2 = *reinterpret_cast<const uint2*>(&PsW[(s << 5) + ((16 + 4*g    ) ^ sx2)]);
      uint2 r3 = *reinterpret_cast<const uint2*>(&PsW[(s << 5) + ((16 + 4*g + 2) ^ sx2)]);
      pa1.u[0] = r2.x; pa1.u[1] = r2.y; pa1.u[2] = r3.x; pa1.u[3] = r3.y;
    }
    // PV: of += mfma(P, Vt)
#pragma unroll
    for (int df=0; df<4; df++){
      int d = df*16 + s;
      bf16x8 v0 = *(const bf16x8*)&Vs[d*64 + ((g ^ (s & 7)) << 3)];
      bf16x8 v1 = *(const bf16x8*)&Vs[d*64 + (((4+g) ^ (s & 7)) << 3)];
      of[df] = __builtin_amdgcn_mfma_f32_16x16x32_bf16(pa0.v, v0, of[df], 0, 0, 0);
      of[df] = __builtin_amdgcn_mfma_f32_16x16x32_bf16(pa1.v, v1, of[df], 0, 0, 0);
    }
  }
  // epilogue: normalize, gate with R, store bf16
  lsum += __shfl_xor(lsum, 16, 64);
  lsum += __shfl_xor(lsum, 32, 64);
  float inv = 1.0f / lsum;
  float ic[4];
#pragma unroll
  for (int r=0;r<4;r++) ic[r] = __shfl(inv, g*4 + r, 64);
#pragma unroll
  for (int df=0; df<4; df++){
#pragma unroll
    for (int r=0;r<4;r++){
      size_t row = (size_t)(q0 + w*16 + g*4 + r);
      size_t idx = base + (row << 10) + colh + df*16 + s;
      float o = of[df][r] * ic[r];
      float rg = bf2f(rp[idx]);
      gated[idx] = f2bf(o * rg);
    }
  }
}

extern "C" void kernel_launch(void* const* d_in, const int* in_sizes, int n_in,
                              void* d_out, int out_size, void* d_ws, size_t ws_size,
                              hipStream_t stream){
  (void)in_sizes; (void)n_in; (void)out_size; (void)ws_size;
  const float* value = (const float*)d_in[0];
  const float* key   = (const float*)d_in[1];
  const float* query = (const float*)d_in[2];
  const float* Wq = (const float*)d_in[3];  const float* bq = (const float*)d_in[4];
  const float* Wk = (const float*)d_in[5];  const float* bk = (const float*)d_in[6];
  const float* Wv = (const float*)d_in[7];  const float* bv = (const float*)d_in[8];
  const float* Wr = (const float*)d_in[9];  const float* br = (const float*)d_in[10];
  const float* Wo = (const float*)d_in[11]; const float* bo = (const float*)d_in[12];

  char* ws = (char*)d_ws;
  const size_t MB = (size_t)1 << 20;
  u16* qb  = (u16*)(ws + 0*MB);      // 16 MB each (bf16 activations)
  u16* kb  = (u16*)(ws + 16*MB);
  u16* vb  = (u16*)(ws + 32*MB);
  u16* wqt = (u16*)(ws + 48*MB);     // 2 MB each (bf16 transposed weights)
  u16* wkt = (u16*)(ws + 50*MB);
  u16* wvt = (u16*)(ws + 52*MB);
  u16* wrt = (u16*)(ws + 54*MB);
  u16* wot = (u16*)(ws + 56*MB);
  u16* qpj = (u16*)(ws + 58*MB);     // 16 MB each (bf16 projections)
  u16* kpj = (u16*)(ws + 74*MB);
  u16* vtg = (u16*)(ws + 90*MB);     // V projection, pre-transposed [(b*16+h)*64+d][sq]
  u16* rpj = (u16*)(ws + 106*MB);
  u16* gat = qb;                     // alias: qb dead after projections

  k_cvt_act<<<dim3(4096, 3), 256, 0, stream>>>(value, key, query, vb, kb, qb);
  k_cvt_wt<<<dim3(32, 32, 5), dim3(32, 8), 0, stream>>>(Wq, Wk, Wv, Wr, Wo,
                                                        wqt, wkt, wvt, wrt, wot);
  k_gemm<0><<<dim3(64, 8), 256, 0, stream>>>(qb, wqt, bq, qpj);
  k_gemm<0><<<dim3(64, 8), 256, 0, stream>>>(qb, wrt, br, rpj);
  k_gemm<0><<<dim3(64, 8), 256, 0, stream>>>(kb, wkt, bk, kpj);
  k_gemm<2><<<dim3(64, 8), 256, 0, stream>>>(vb, wvt, bv, vtg);
  k_attn<<<dim3(16, 128), 256, 0, stream>>>(qpj, kpj, vtg, rpj, gat);
  k_gemm<1><<<dim3(64, 8), 256, 0, stream>>>(gat, wot, bo, d_out);
}

// Round 4
// 210.234 us; speedup vs baseline: 1.2536x; 1.0659x over previous
//
#include <hip/hip_runtime.h>
#include <stdint.h>

#define B_ 8
#define S_ 1024
#define DM_ 1024
#define H_ 16
#define DH_ 64
#define M_ (B_*S_)

typedef unsigned short u16;
typedef unsigned int u32;
typedef __attribute__((ext_vector_type(8))) short bf16x8;
typedef __attribute__((ext_vector_type(4))) float f32x4;

__device__ __forceinline__ u16 f2bf(float f){
  union { float f; u32 u; } x; x.f = f;
  u32 r = x.u + 0x7fffu + ((x.u >> 16) & 1u);
  return (u16)(r >> 16);
}
__device__ __forceinline__ float bf2f(u16 u){
  union { u32 u; float f; } x; x.u = ((u32)u) << 16; return x.f;
}
__device__ __forceinline__ u32 cvtpk(float lo, float hi){
  u32 r; asm("v_cvt_pk_bf16_f32 %0, %1, %2" : "=v"(r) : "v"(lo), "v"(hi)); return r;
}
__device__ __forceinline__ void gload16(const void* g, void* l){
  __builtin_amdgcn_global_load_lds((const __attribute__((address_space(1))) void*)g,
                                   (__attribute__((address_space(3))) void*)l, 16, 0, 0);
}

// ---------------- convert activations fp32 -> bf16 ----------------
__global__ void k_cvt_act(const float* __restrict__ v, const float* __restrict__ k,
                          const float* __restrict__ q, u16* __restrict__ vb,
                          u16* __restrict__ kb, u16* __restrict__ qb){
  int z = blockIdx.y;
  const float* src = (z == 0) ? v : (z == 1) ? k : q;
  u16* dst = (z == 0) ? vb : (z == 1) ? kb : qb;
  size_t i = ((size_t)blockIdx.x * blockDim.x + threadIdx.x) * 8;
  float4 a = *(const float4*)(src + i);
  float4 b = *(const float4*)(src + i + 4);
  uint4 o;
  o.x = (u32)f2bf(a.x) | ((u32)f2bf(a.y) << 16);
  o.y = (u32)f2bf(a.z) | ((u32)f2bf(a.w) << 16);
  o.z = (u32)f2bf(b.x) | ((u32)f2bf(b.y) << 16);
  o.w = (u32)f2bf(b.z) | ((u32)f2bf(b.w) << 16);
  *(uint4*)(dst + i) = o;
}

// -------- convert + transpose weights fp32[K][N] -> bf16[N][K]; z<4 into wall chunks --------
__global__ void k_cvt_wt(const float* __restrict__ w0, const float* __restrict__ w1,
                         const float* __restrict__ w2, const float* __restrict__ w3,
                         const float* __restrict__ w4,
                         u16* __restrict__ wall, u16* __restrict__ wot){
  __shared__ float tile[32][33];
  int z = blockIdx.z;
  const float* src = (z==0)?w0:(z==1)?w1:(z==2)?w2:(z==3)?w3:w4;
  u16* dst = (z<4) ? (wall + (size_t)z * 1048576) : wot;
  int n0 = blockIdx.x * 32, k0 = blockIdx.y * 32;
  int tx = threadIdx.x, ty = threadIdx.y;
#pragma unroll
  for (int i=0;i<4;i++) tile[ty+8*i][tx] = src[(size_t)(k0+ty+8*i)*DM_ + n0+tx];
  __syncthreads();
#pragma unroll
  for (int i=0;i<4;i++) dst[(size_t)(n0+ty+8*i)*DM_ + k0+tx] = f2bf(tile[tx][ty+8*i]);
}

// ---------------- fused projection GEMM: 4 chunks of N (Q,R,K,V) in one launch ----------------
// grid (64, 32): bx = m-tile, by = n-tile; chunk = by>>3. V chunk writes transposed.
__global__ __launch_bounds__(256) void k_proj(const u16* __restrict__ qb, const u16* __restrict__ kb,
                                              const u16* __restrict__ vb, const u16* __restrict__ wall,
                                              const float* __restrict__ bqp, const float* __restrict__ brp,
                                              const float* __restrict__ bkp, const float* __restrict__ bvp,
                                              u16* __restrict__ qpj, u16* __restrict__ rpj,
                                              u16* __restrict__ kpj, u16* __restrict__ vtg){
  __shared__ u16 As[128*64];
  __shared__ u16 Bs[128*64];
  const int tid = threadIdx.x;
  const int w = tid >> 6, l = tid & 63, g = l >> 4, s = l & 15;
  const int wr = w >> 1, wc = w & 1;
  const int m0 = blockIdx.x << 7;
  const int ng0 = blockIdx.y << 7;            // global n within 4096
  const int chunk = ng0 >> 10;
  const u16* A = (chunk < 2) ? qb : (chunk == 2) ? kb : vb;
  const float* bias = (chunk==0)?bqp:(chunk==1)?brp:(chunk==2)?bkp:bvp;
  f32x4 acc[4][4];
#pragma unroll
  for (int i=0;i<4;i++)
#pragma unroll
    for (int j=0;j<4;j++) acc[i][j] = (f32x4){0.f,0.f,0.f,0.f};

  for (int k0 = 0; k0 < 1024; k0 += 64){
    __syncthreads();
#pragma unroll
    for (int i=0;i<4;i++){
      int c = tid + i*256;
      int m = c >> 3, slot = c & 7;
      gload16(A + ((size_t)(m0+m) << 10) + (k0 + ((slot ^ (m & 7)) << 3)),
              &As[(i*256 + w*64) * 8]);
    }
#pragma unroll
    for (int i=0;i<4;i++){
      int c = tid + i*256;
      int n = c >> 3, slot = c & 7;
      gload16(wall + ((size_t)(ng0+n) << 10) + (k0 + ((slot ^ (n & 7)) << 3)),
              &Bs[(i*256 + w*64) * 8]);
    }
    __syncthreads();
#pragma unroll
    for (int ks=0; ks<2; ks++){
      bf16x8 af[4], bfv[4];
#pragma unroll
      for (int mi=0;mi<4;mi++){
        int m = wr*64 + mi*16 + s;
        af[mi] = *(const bf16x8*)&As[m*64 + (((ks*4+g) ^ (s & 7)) << 3)];
      }
#pragma unroll
      for (int ni=0;ni<4;ni++){
        int n = wc*64 + ni*16 + s;
        bfv[ni] = *(const bf16x8*)&Bs[n*64 + (((ks*4+g) ^ (s & 7)) << 3)];
      }
#pragma unroll
      for (int mi=0;mi<4;mi++)
#pragma unroll
        for (int ni=0;ni<4;ni++)
          acc[mi][ni] = __builtin_amdgcn_mfma_f32_16x16x32_bf16(af[mi], bfv[ni], acc[mi][ni], 0, 0, 0);
    }
  }
  u16* outp = (chunk==0)?qpj:(chunk==1)?rpj:kpj;
#pragma unroll
  for (int ni=0;ni<4;ni++){
    int cg = ng0 + wc*64 + ni*16 + s;
    int col = cg & 1023;
    float bv = bias[col];
#pragma unroll
    for (int mi=0;mi<4;mi++){
      int row = m0 + wr*64 + mi*16 + g*4;
      if (chunk == 3){
        union { short4 v; u16 e[4]; } pk;
#pragma unroll
        for (int r=0;r<4;r++) pk.e[r] = f2bf(acc[mi][ni][r] + bv);
        size_t vrow = ((size_t)(row >> 10) * 16 + (col >> 6)) * 64 + (col & 63);
        *(short4*)&vtg[(vrow << 10) + (row & 1023)] = pk.v;
      } else {
#pragma unroll
        for (int r=0;r<4;r++)
          outp[((size_t)(row+r) << 10) + col] = f2bf(acc[mi][ni][r] + bv);
      }
    }
  }
}

// ---------------- output GEMM: Out[M][1024] = A @ Bt^T + bias (f32 out) ----------------
__global__ __launch_bounds__(256) void k_gemm_out(const u16* __restrict__ A, const u16* __restrict__ Bt,
                                                  const float* __restrict__ bias, float* __restrict__ Out){
  __shared__ u16 As[128*64];
  __shared__ u16 Bs[128*64];
  const int tid = threadIdx.x;
  const int w = tid >> 6, l = tid & 63, g = l >> 4, s = l & 15;
  const int wr = w >> 1, wc = w & 1;
  const int m0 = blockIdx.x << 7, n0 = blockIdx.y << 7;
  f32x4 acc[4][4];
#pragma unroll
  for (int i=0;i<4;i++)
#pragma unroll
    for (int j=0;j<4;j++) acc[i][j] = (f32x4){0.f,0.f,0.f,0.f};

  for (int k0 = 0; k0 < 1024; k0 += 64){
    __syncthreads();
#pragma unroll
    for (int i=0;i<4;i++){
      int c = tid + i*256;
      int m = c >> 3, slot = c & 7;
      gload16(A + ((size_t)(m0+m) << 10) + (k0 + ((slot ^ (m & 7)) << 3)),
              &As[(i*256 + w*64) * 8]);
    }
#pragma unroll
    for (int i=0;i<4;i++){
      int c = tid + i*256;
      int n = c >> 3, slot = c & 7;
      gload16(Bt + ((size_t)(n0+n) << 10) + (k0 + ((slot ^ (n & 7)) << 3)),
              &Bs[(i*256 + w*64) * 8]);
    }
    __syncthreads();
#pragma unroll
    for (int ks=0; ks<2; ks++){
      bf16x8 af[4], bfv[4];
#pragma unroll
      for (int mi=0;mi<4;mi++){
        int m = wr*64 + mi*16 + s;
        af[mi] = *(const bf16x8*)&As[m*64 + (((ks*4+g) ^ (s & 7)) << 3)];
      }
#pragma unroll
      for (int ni=0;ni<4;ni++){
        int n = wc*64 + ni*16 + s;
        bfv[ni] = *(const bf16x8*)&Bs[n*64 + (((ks*4+g) ^ (s & 7)) << 3)];
      }
#pragma unroll
      for (int mi=0;mi<4;mi++)
#pragma unroll
        for (int ni=0;ni<4;ni++)
          acc[mi][ni] = __builtin_amdgcn_mfma_f32_16x16x32_bf16(af[mi], bfv[ni], acc[mi][ni], 0, 0, 0);
    }
  }
#pragma unroll
  for (int ni=0;ni<4;ni++){
    int col = n0 + wc*64 + ni*16 + s;
    float bv = bias[col];
#pragma unroll
    for (int mi=0;mi<4;mi++){
      int row = m0 + wr*64 + mi*16 + g*4;
#pragma unroll
      for (int r=0;r<4;r++)
        Out[((size_t)(row+r) << 10) + col] = acc[mi][ni][r] + bv;
    }
  }
}

// ---------------- flash attention + R-gating (swapped QK^T, dbuf prefetch, defer-max) ----------
// grid: 2048 1-D (XCD-swizzled). block 256. Each wave owns 16 q-rows.
__global__ __launch_bounds__(256) void k_attn(const u16* __restrict__ qp, const u16* __restrict__ kp,
                                              const u16* __restrict__ vtg, const u16* __restrict__ rp,
                                              u16* __restrict__ gated){
  __shared__ u16 Ks[2][64*64];     // [sj][d], k-slot XOR-swizzled (involution slot^(sj&7))
  __shared__ u16 Vs[2][64*64];     // [d][sj], sj-slot XOR-swizzled (involution slot^(d&7))
  __shared__ u32 PsU[4*16*32];     // per-wave P rows, XOR-banked
  const int tid = threadIdx.x;
  const int w = tid >> 6, l = tid & 63, g = l >> 4, s = l & 15;
  const int bid = blockIdx.x;
  const int swz = (bid & 7) * 256 + (bid >> 3);   // XCD-aware (2048 % 8 == 0, bijective)
  const int q0 = (swz & 15) << 6;
  const int bh = swz >> 4;
  const int b = bh >> 4, h = bh & 15;
  const size_t base = ((size_t)b << 20);
  const int colh = h << 6;
  const float KL = 1.4426950408889634f / 32.0f;   // log2(e)/SCALE

  const size_t qoff = base + ((size_t)(q0 + w*16 + s) << 10) + colh;
  bf16x8 qf0 = *(const bf16x8*)(qp + qoff + g*8);
  bf16x8 qf1 = *(const bf16x8*)(qp + qoff + 32 + g*8);
  const size_t vbase = ((size_t)(b*16 + h)) << 16;

  u32* PsW = PsU + (w << 9);
  const int sx2 = s << 1;

  float mrun = -1e30f, lsum = 0.f;
  f32x4 of[4];
#pragma unroll
  for (int d=0;d<4;d++) of[d] = (f32x4){0.f,0.f,0.f,0.f};

#define STAGE_KV(BUF, KV0) do { \
    _Pragma("unroll") \
    for (int i=0;i<2;i++){ \
      int c = tid + i*256; \
      int sj = c >> 3, slot = c & 7; \
      gload16(kp + base + ((size_t)((KV0)+sj) << 10) + colh + ((slot ^ (sj & 7)) << 3), \
              &Ks[BUF][(i*256 + w*64) * 8]); \
    } \
    _Pragma("unroll") \
    for (int i=0;i<2;i++){ \
      int c = tid + i*256; \
      int d = c >> 3, slot = c & 7; \
      gload16(vtg + vbase + ((size_t)d << 10) + (KV0) + ((slot ^ (d & 7)) << 3), \
              &Vs[BUF][(i*256 + w*64) * 8]); \
    } \
  } while(0)

  STAGE_KV(0, 0);
  __syncthreads();

  int cur = 0;
  for (int t = 0; t < 16; t++){
    if (t < 15) STAGE_KV(cur ^ 1, (t+1) << 6);   // prefetch next tile; flies during compute
    const u16* ksb = Ks[cur];
    const u16* vsb = Vs[cur];

    // swapped QK^T: lane (g,s) holds E[sj=16*sjf+4g+r][si=s]
    f32x4 e2[4];
#pragma unroll
    for (int sjf=0;sjf<4;sjf++){
      e2[sjf] = (f32x4){0.f,0.f,0.f,0.f};
      int sj = sjf*16 + s;
      bf16x8 kf0 = *(const bf16x8*)&ksb[sj*64 + ((g ^ (s & 7)) << 3)];
      e2[sjf] = __builtin_amdgcn_mfma_f32_16x16x32_bf16(kf0, qf0, e2[sjf], 0, 0, 0);
      bf16x8 kf1 = *(const bf16x8*)&ksb[sj*64 + (((4+g) ^ (s & 7)) << 3)];
      e2[sjf] = __builtin_amdgcn_mfma_f32_16x16x32_bf16(kf1, qf1, e2[sjf], 0, 0, 0);
    }
    // row max (v_max3-friendly triples), reduce across g-groups
    float rm = fmaxf(fmaxf(e2[0][0], e2[0][1]), e2[0][2]);
    rm = fmaxf(fmaxf(rm, e2[0][3]), e2[1][0]);
    rm = fmaxf(fmaxf(rm, e2[1][1]), e2[1][2]);
    rm = fmaxf(fmaxf(rm, e2[1][3]), e2[2][0]);
    rm = fmaxf(fmaxf(rm, e2[2][1]), e2[2][2]);
    rm = fmaxf(fmaxf(rm, e2[2][3]), e2[3][0]);
    rm = fmaxf(fmaxf(rm, e2[3][1]), e2[3][2]);
    rm = fmaxf(rm, e2[3][3]);
    rm = fmaxf(rm, __shfl_xor(rm, 16, 64));
    rm = fmaxf(rm, __shfl_xor(rm, 32, 64));
    // defer-max: skip rescale while growth <= 8 in log2 domain (P bounded by 256)
    if (!__all(rm <= mrun + 177.0f)){
      float nm = fmaxf(mrun, rm);
      float alpha = __builtin_amdgcn_exp2f((mrun - nm) * KL);
      mrun = nm;
      lsum *= alpha;
      float ac[4];
#pragma unroll
      for (int r=0;r<4;r++) ac[r] = __shfl(alpha, g*4 + r, 64);
#pragma unroll
      for (int d=0; d<4; d++)
#pragma unroll
        for (int r=0;r<4;r++) of[d][r] *= ac[r];
    }

    const float mk = mrun * KL;
#pragma unroll
    for (int sjf=0;sjf<4;sjf++){
      float p0 = __builtin_amdgcn_exp2f(e2[sjf][0]*KL - mk);
      float p1 = __builtin_amdgcn_exp2f(e2[sjf][1]*KL - mk);
      float p2 = __builtin_amdgcn_exp2f(e2[sjf][2]*KL - mk);
      float p3 = __builtin_amdgcn_exp2f(e2[sjf][3]*KL - mk);
      lsum += (p0 + p1) + (p2 + p3);
      uint2 pk; pk.x = cvtpk(p0, p1); pk.y = cvtpk(p2, p3);
      int phys = (8*sjf + 2*g) ^ sx2;
      *reinterpret_cast<uint2*>(&PsW[(s << 5) + phys]) = pk;
    }
    union { u32 u[4]; bf16x8 v; } pa0, pa1;
    {
      uint2 r0 = *reinterpret_cast<const uint2*>(&PsW[(s << 5) + ((4*g    ) ^ sx2)]);
      uint2 r1 = *reinterpret_cast<const uint2*>(&PsW[(s << 5) + ((4*g + 2) ^ sx2)]);
      pa0.u[0] = r0.x; pa0.u[1] = r0.y; pa0.u[2] = r1.x; pa0.u[3] = r1.y;
      uint2 r2 = *reinterpret_cast<const uint2*>(&PsW[(s << 5) + ((16 + 4*g    ) ^ sx2)]);
      uint2 r3 = *reinterpret_cast<const uint2*>(&PsW[(s << 5) + ((16 + 4*g + 2) ^ sx2)]);
      pa1.u[0] = r2.x; pa1.u[1] = r2.y; pa1.u[2] = r3.x; pa1.u[3] = r3.y;
    }
#pragma unroll
    for (int df=0; df<4; df++){
      int d = df*16 + s;
      bf16x8 v0 = *(const bf16x8*)&vsb[d*64 + ((g ^ (s & 7)) << 3)];
      bf16x8 v1 = *(const bf16x8*)&vsb[d*64 + (((4+g) ^ (s & 7)) << 3)];
      of[df] = __builtin_amdgcn_mfma_f32_16x16x32_bf16(pa0.v, v0, of[df], 0, 0, 0);
      of[df] = __builtin_amdgcn_mfma_f32_16x16x32_bf16(pa1.v, v1, of[df], 0, 0, 0);
    }
    __syncthreads();   // drains vmcnt(0): next tile staged + all waves done reading cur
    cur ^= 1;
  }
#undef STAGE_KV

  // epilogue: normalize, gate with R, store bf16
  lsum += __shfl_xor(lsum, 16, 64);
  lsum += __shfl_xor(lsum, 32, 64);
  float inv = 1.0f / lsum;
  float ic[4];
#pragma unroll
  for (int r=0;r<4;r++) ic[r] = __shfl(inv, g*4 + r, 64);
#pragma unroll
  for (int df=0; df<4; df++){
#pragma unroll
    for (int r=0;r<4;r++){
      size_t row = (size_t)(q0 + w*16 + g*4 + r);
      size_t idx = base + (row << 10) + colh + df*16 + s;
      float o = of[df][r] * ic[r];
      float rg = bf2f(rp[idx]);
      gated[idx] = f2bf(o * rg);
    }
  }
}

extern "C" void kernel_launch(void* const* d_in, const int* in_sizes, int n_in,
                              void* d_out, int out_size, void* d_ws, size_t ws_size,
                              hipStream_t stream){
  (void)in_sizes; (void)n_in; (void)out_size; (void)ws_size;
  const float* value = (const float*)d_in[0];
  const float* key   = (const float*)d_in[1];
  const float* query = (const float*)d_in[2];
  const float* Wq = (const float*)d_in[3];  const float* bq = (const float*)d_in[4];
  const float* Wk = (const float*)d_in[5];  const float* bk = (const float*)d_in[6];
  const float* Wv = (const float*)d_in[7];  const float* bv = (const float*)d_in[8];
  const float* Wr = (const float*)d_in[9];  const float* br = (const float*)d_in[10];
  const float* Wo = (const float*)d_in[11]; const float* bo = (const float*)d_in[12];

  char* ws = (char*)d_ws;
  const size_t MB = (size_t)1 << 20;
  u16* qb   = (u16*)(ws + 0*MB);     // 16 MB each (bf16 activations)
  u16* kb   = (u16*)(ws + 16*MB);
  u16* vb   = (u16*)(ws + 32*MB);
  u16* wall = (u16*)(ws + 48*MB);    // 8 MB: [Wq^T | Wr^T | Wk^T | Wv^T] bf16 [4096][1024]
  u16* wot  = (u16*)(ws + 56*MB);    // 2 MB
  u16* qpj  = (u16*)(ws + 58*MB);    // 16 MB each
  u16* kpj  = (u16*)(ws + 74*MB);
  u16* vtg  = (u16*)(ws + 90*MB);    // V projection, pre-transposed [(b*16+h)*64+d][sq]
  u16* rpj  = (u16*)(ws + 106*MB);
  u16* gat  = qb;                    // alias: qb dead after projections

  k_cvt_act<<<dim3(4096, 3), 256, 0, stream>>>(value, key, query, vb, kb, qb);
  k_cvt_wt<<<dim3(32, 32, 5), dim3(32, 8), 0, stream>>>(Wq, Wr, Wk, Wv, Wo, wall, wot);
  k_proj<<<dim3(64, 32), 256, 0, stream>>>(qb, kb, vb, wall, bq, br, bk, bv,
                                           qpj, rpj, kpj, vtg);
  k_attn<<<2048, 256, 0, stream>>>(qpj, kpj, vtg, rpj, gat);
  k_gemm_out<<<dim3(64, 8), 256, 0, stream>>>(gat, wot, bo, (float*)d_out);
}

// Round 5
// 197.739 us; speedup vs baseline: 1.3328x; 1.0632x over previous
//
#include <hip/hip_runtime.h>
#include <stdint.h>

#define B_ 8
#define S_ 1024
#define DM_ 1024
#define H_ 16
#define DH_ 64
#define M_ (B_*S_)

typedef unsigned short u16;
typedef unsigned int u32;
typedef __attribute__((ext_vector_type(8))) short bf16x8;
typedef __attribute__((ext_vector_type(4))) float f32x4;

__device__ __forceinline__ u16 f2bf(float f){
  union { float f; u32 u; } x; x.f = f;
  u32 r = x.u + 0x7fffu + ((x.u >> 16) & 1u);
  return (u16)(r >> 16);
}
__device__ __forceinline__ float bf2f(u16 u){
  union { u32 u; float f; } x; x.u = ((u32)u) << 16; return x.f;
}
__device__ __forceinline__ u32 cvtpk(float lo, float hi){
  u32 r; asm("v_cvt_pk_bf16_f32 %0, %1, %2" : "=v"(r) : "v"(lo), "v"(hi)); return r;
}
__device__ __forceinline__ void gload16(const void* g, void* l){
  __builtin_amdgcn_global_load_lds((const __attribute__((address_space(1))) void*)g,
                                   (__attribute__((address_space(3))) void*)l, 16, 0, 0);
}

// ---------------- convert activations fp32 -> bf16 ----------------
__global__ void k_cvt_act(const float* __restrict__ v, const float* __restrict__ k,
                          const float* __restrict__ q, u16* __restrict__ vb,
                          u16* __restrict__ kb, u16* __restrict__ qb){
  int z = blockIdx.y;
  const float* src = (z == 0) ? v : (z == 1) ? k : q;
  u16* dst = (z == 0) ? vb : (z == 1) ? kb : qb;
  size_t i = ((size_t)blockIdx.x * blockDim.x + threadIdx.x) * 8;
  float4 a = *(const float4*)(src + i);
  float4 b = *(const float4*)(src + i + 4);
  uint4 o;
  o.x = (u32)f2bf(a.x) | ((u32)f2bf(a.y) << 16);
  o.y = (u32)f2bf(a.z) | ((u32)f2bf(a.w) << 16);
  o.z = (u32)f2bf(b.x) | ((u32)f2bf(b.y) << 16);
  o.w = (u32)f2bf(b.z) | ((u32)f2bf(b.w) << 16);
  *(uint4*)(dst + i) = o;
}

// -------- convert + transpose weights fp32[K][N] -> bf16[N][K]; z<4 into wall chunks --------
__global__ void k_cvt_wt(const float* __restrict__ w0, const float* __restrict__ w1,
                         const float* __restrict__ w2, const float* __restrict__ w3,
                         const float* __restrict__ w4,
                         u16* __restrict__ wall, u16* __restrict__ wot){
  __shared__ float tile[32][33];
  int z = blockIdx.z;
  const float* src = (z==0)?w0:(z==1)?w1:(z==2)?w2:(z==3)?w3:w4;
  u16* dst = (z<4) ? (wall + (size_t)z * 1048576) : wot;
  int n0 = blockIdx.x * 32, k0 = blockIdx.y * 32;
  int tx = threadIdx.x, ty = threadIdx.y;
#pragma unroll
  for (int i=0;i<4;i++) tile[ty+8*i][tx] = src[(size_t)(k0+ty+8*i)*DM_ + n0+tx];
  __syncthreads();
#pragma unroll
  for (int i=0;i<4;i++) dst[(size_t)(n0+ty+8*i)*DM_ + k0+tx] = f2bf(tile[tx][ty+8*i]);
}

// ======== fused projection GEMM, 256x256 tile, BK=64, 8-phase counted-vmcnt schedule ========
// grid (32, 16), 512 threads (8 waves: 2M x 4N, 128x64 per wave). LDS 128KB dynamic (2 dbuf).
// Stage slots per iter (tiles t=2it in X=buf0, t+1 in Y=buf1):
//   P1: Y.A-h0(t+1)  P2: Y.A-h1(t+1)  P3: X.B-h0(t+2)  P4: X.B-h1(t+2)
//   P5: X.A-h0(t+2)  P6: X.A-h1(t+2)  P7: Y.B-h0(t+3)  P8: Y.B-h1(t+3)
// vmcnt(4) at P4 (-> Y complete) and P8 (-> X complete); vmcnt(0) at P4 on last iter.
__global__ __launch_bounds__(512, 2) void k_proj8(const u16* __restrict__ qb, const u16* __restrict__ kb,
                                                  const u16* __restrict__ vb, const u16* __restrict__ wall,
                                                  const float* __restrict__ bqp, const float* __restrict__ brp,
                                                  const float* __restrict__ bkp, const float* __restrict__ bvp,
                                                  u16* __restrict__ qpj, u16* __restrict__ rpj,
                                                  u16* __restrict__ kpj, u16* __restrict__ vtg){
  extern __shared__ u16 smem[];
  u16* As = smem;                 // [2][256][64]
  u16* Bs = smem + 32768;         // [2][256][64]
  const int tid = threadIdx.x;
  const int w = tid >> 6, l = tid & 63, g = l >> 4, s = l & 15;
  const int wr = w >> 2, wc = w & 3;
  const int m0 = blockIdx.x << 8;
  const int ng0 = blockIdx.y << 8;
  const int chunk = ng0 >> 10;
  const u16* A = (chunk < 2) ? qb : (chunk == 2) ? kb : vb;

  f32x4 acc[8][4];
#pragma unroll
  for (int i=0;i<8;i++)
#pragma unroll
    for (int j=0;j<4;j++) acc[i][j] = (f32x4){0.f,0.f,0.f,0.f};

#define PSTAGE_A(buf, tile, h) do { \
    int k0s = (tile) << 6; \
    _Pragma("unroll") \
    for (int i2 = 0; i2 < 2; i2++){ \
      int c = tid + i2*512; int rw = c >> 3, sl = c & 7; \
      gload16(A + ((size_t)(m0 + (h)*128 + rw) << 10) + k0s + ((sl ^ (rw & 7)) << 3), \
              &As[(buf)*16384 + (h)*8192 + (i2*512 + w*64)*8]); \
    } } while(0)

#define PSTAGE_B(buf, tile, h) do { \
    int k0s = (tile) << 6; \
    _Pragma("unroll") \
    for (int i2 = 0; i2 < 2; i2++){ \
      int c = tid + i2*512; int rw = c >> 3, sl = c & 7; \
      gload16(wall + ((size_t)(ng0 + (h)*128 + rw) << 10) + k0s + ((sl ^ (rw & 7)) << 3), \
              &Bs[(buf)*16384 + (h)*8192 + (i2*512 + w*64)*8]); \
    } } while(0)

#define PLOADA(cb, mh) do { \
    _Pragma("unroll") for (int mi2=0; mi2<4; mi2++) \
    _Pragma("unroll") for (int ks=0; ks<2; ks++){ \
      int rw = wr*128 + (mh)*64 + mi2*16 + s; \
      af[mi2][ks] = *(const bf16x8*)&As[(cb)*16384 + rw*64 + (((ks*4+g) ^ (s&7)) << 3)]; \
    } } while(0)

#define PLOADB(dst, cb, nh) do { \
    _Pragma("unroll") for (int ni2=0; ni2<2; ni2++) \
    _Pragma("unroll") for (int ks=0; ks<2; ks++){ \
      int rw = wc*64 + (nh)*32 + ni2*16 + s; \
      dst[ni2][ks] = *(const bf16x8*)&Bs[(cb)*16384 + rw*64 + (((ks*4+g) ^ (s&7)) << 3)]; \
    } } while(0)

#define PMFMA(mh, nh, bfr) do { \
    _Pragma("unroll") for (int mi2=0; mi2<4; mi2++) \
    _Pragma("unroll") for (int ni2=0; ni2<2; ni2++) \
    _Pragma("unroll") for (int ks=0; ks<2; ks++) \
      acc[(mh)*4+mi2][(nh)*2+ni2] = __builtin_amdgcn_mfma_f32_16x16x32_bf16( \
          af[mi2][ks], bfr[ni2][ks], acc[(mh)*4+mi2][(nh)*2+ni2], 0, 0, 0); \
    } while(0)

#define BAR   __builtin_amdgcn_s_barrier()
#define PRIO1 __builtin_amdgcn_s_setprio(1)
#define PRIO0 __builtin_amdgcn_s_setprio(0)

  // prologue: X <- tile0 (4 halves), Y <- tile1 B-halves
  PSTAGE_A(0, 0, 0); PSTAGE_A(0, 0, 1); PSTAGE_B(0, 0, 0); PSTAGE_B(0, 0, 1);
  PSTAGE_B(1, 1, 0); PSTAGE_B(1, 1, 1);
  asm volatile("s_waitcnt vmcnt(4)" ::: "memory");   // X fully landed
  BAR;

#pragma unroll 1
  for (int it = 0; it < 8; ++it){
    const int tB = 2*it + 1, t2 = 2*it + 2, t3 = 2*it + 3;
    const bool pre = (it < 7);
    {
      bf16x8 af[4][2], bf0[2][2], bf1[2][2];
      // P1
      PLOADA(0, 0); PLOADB(bf0, 0, 0);
      PSTAGE_A(1, tB, 0);
      BAR; PRIO1; PMFMA(0, 0, bf0); PRIO0; BAR;
      // P2
      PLOADB(bf1, 0, 1);
      PSTAGE_A(1, tB, 1);
      BAR; PRIO1; PMFMA(0, 1, bf1); PRIO0; BAR;
      // P3
      PLOADA(0, 1);
      if (pre) PSTAGE_B(0, t2, 0);
      BAR; PRIO1; PMFMA(1, 1, bf1); PRIO0; BAR;
      // P4
      if (pre) PSTAGE_B(0, t2, 1);
      BAR; PRIO1; PMFMA(1, 0, bf0); PRIO0;
      if (it == 7) asm volatile("s_waitcnt vmcnt(0)" ::: "memory");
      else         asm volatile("s_waitcnt vmcnt(4)" ::: "memory");
      BAR;
    }
    {
      bf16x8 af[4][2], bf0[2][2], bf1[2][2];
      // P5
      PLOADA(1, 0); PLOADB(bf0, 1, 0);
      if (pre) PSTAGE_A(0, t2, 0);
      BAR; PRIO1; PMFMA(0, 0, bf0); PRIO0; BAR;
      // P6
      PLOADB(bf1, 1, 1);
      if (pre) PSTAGE_A(0, t2, 1);
      BAR; PRIO1; PMFMA(0, 1, bf1); PRIO0; BAR;
      // P7
      PLOADA(1, 1);
      if (pre) PSTAGE_B(1, t3, 0);
      BAR; PRIO1; PMFMA(1, 1, bf1); PRIO0; BAR;
      // P8
      if (pre) PSTAGE_B(1, t3, 1);
      BAR; PRIO1; PMFMA(1, 0, bf0); PRIO0;
      asm volatile("s_waitcnt vmcnt(4)" ::: "memory");
      BAR;
    }
  }

  // epilogue
  const float* bias = (chunk==0)?bqp:(chunk==1)?brp:(chunk==2)?bkp:bvp;
  u16* outp = (chunk==0)?qpj:(chunk==1)?rpj:kpj;
#pragma unroll
  for (int ni=0; ni<4; ni++){
    int cg = ng0 + wc*64 + ni*16 + s;
    int col = cg & 1023;
    float bv = bias[col];
#pragma unroll
    for (int mi=0; mi<8; mi++){
      int row = m0 + wr*128 + mi*16 + g*4;
      if (chunk == 3){
        union { short4 v; u16 e[4]; } pk2;
#pragma unroll
        for (int r=0;r<4;r++) pk2.e[r] = f2bf(acc[mi][ni][r] + bv);
        size_t vrow = ((size_t)(row >> 10) * 16 + (col >> 6)) * 64 + (col & 63);
        *(short4*)&vtg[(vrow << 10) + (row & 1023)] = pk2.v;
      } else {
#pragma unroll
        for (int r=0;r<4;r++)
          outp[((size_t)(row+r) << 10) + col] = f2bf(acc[mi][ni][r] + bv);
      }
    }
  }
#undef PSTAGE_A
#undef PSTAGE_B
#undef PLOADA
#undef PLOADB
#undef PMFMA
#undef BAR
#undef PRIO1
#undef PRIO0
}

// ---------------- output GEMM: Out[M][1024] = A @ Bt^T + bias (f32 out) ----------------
__global__ __launch_bounds__(256) void k_gemm_out(const u16* __restrict__ A, const u16* __restrict__ Bt,
                                                  const float* __restrict__ bias, float* __restrict__ Out){
  __shared__ u16 As[128*64];
  __shared__ u16 Bs[128*64];
  const int tid = threadIdx.x;
  const int w = tid >> 6, l = tid & 63, g = l >> 4, s = l & 15;
  const int wr = w >> 1, wc = w & 1;
  const int m0 = blockIdx.x << 7, n0 = blockIdx.y << 7;
  f32x4 acc[4][4];
#pragma unroll
  for (int i=0;i<4;i++)
#pragma unroll
    for (int j=0;j<4;j++) acc[i][j] = (f32x4){0.f,0.f,0.f,0.f};

  for (int k0 = 0; k0 < 1024; k0 += 64){
    __syncthreads();
#pragma unroll
    for (int i=0;i<4;i++){
      int c = tid + i*256;
      int m = c >> 3, slot = c & 7;
      gload16(A + ((size_t)(m0+m) << 10) + (k0 + ((slot ^ (m & 7)) << 3)),
              &As[(i*256 + w*64) * 8]);
    }
#pragma unroll
    for (int i=0;i<4;i++){
      int c = tid + i*256;
      int n = c >> 3, slot = c & 7;
      gload16(Bt + ((size_t)(n0+n) << 10) + (k0 + ((slot ^ (n & 7)) << 3)),
              &Bs[(i*256 + w*64) * 8]);
    }
    __syncthreads();
#pragma unroll
    for (int ks=0; ks<2; ks++){
      bf16x8 af[4], bfv[4];
#pragma unroll
      for (int mi=0;mi<4;mi++){
        int m = wr*64 + mi*16 + s;
        af[mi] = *(const bf16x8*)&As[m*64 + (((ks*4+g) ^ (s & 7)) << 3)];
      }
#pragma unroll
      for (int ni=0;ni<4;ni++){
        int n = wc*64 + ni*16 + s;
        bfv[ni] = *(const bf16x8*)&Bs[n*64 + (((ks*4+g) ^ (s & 7)) << 3)];
      }
#pragma unroll
      for (int mi=0;mi<4;mi++)
#pragma unroll
        for (int ni=0;ni<4;ni++)
          acc[mi][ni] = __builtin_amdgcn_mfma_f32_16x16x32_bf16(af[mi], bfv[ni], acc[mi][ni], 0, 0, 0);
    }
  }
#pragma unroll
  for (int ni=0;ni<4;ni++){
    int col = n0 + wc*64 + ni*16 + s;
    float bv = bias[col];
#pragma unroll
    for (int mi=0;mi<4;mi++){
      int row = m0 + wr*64 + mi*16 + g*4;
#pragma unroll
      for (int r=0;r<4;r++)
        Out[((size_t)(row+r) << 10) + col] = acc[mi][ni][r] + bv;
    }
  }
}

// ---------------- flash attention + R-gating (swapped QK^T, dbuf prefetch, defer-max) ----------
__global__ __launch_bounds__(256) void k_attn(const u16* __restrict__ qp, const u16* __restrict__ kp,
                                              const u16* __restrict__ vtg, const u16* __restrict__ rp,
                                              u16* __restrict__ gated){
  __shared__ u16 Ks[2][64*64];
  __shared__ u16 Vs[2][64*64];
  __shared__ u32 PsU[4*16*32];
  const int tid = threadIdx.x;
  const int w = tid >> 6, l = tid & 63, g = l >> 4, s = l & 15;
  const int bid = blockIdx.x;
  const int swz = (bid & 7) * 256 + (bid >> 3);
  const int q0 = (swz & 15) << 6;
  const int bh = swz >> 4;
  const int b = bh >> 4, h = bh & 15;
  const size_t base = ((size_t)b << 20);
  const int colh = h << 6;
  const float KL = 1.4426950408889634f / 32.0f;

  const size_t qoff = base + ((size_t)(q0 + w*16 + s) << 10) + colh;
  bf16x8 qf0 = *(const bf16x8*)(qp + qoff + g*8);
  bf16x8 qf1 = *(const bf16x8*)(qp + qoff + 32 + g*8);
  const size_t vbase = ((size_t)(b*16 + h)) << 16;

  u32* PsW = PsU + (w << 9);
  const int sx2 = s << 1;

  float mrun = -1e30f, lsum = 0.f;
  f32x4 of[4];
#pragma unroll
  for (int d=0;d<4;d++) of[d] = (f32x4){0.f,0.f,0.f,0.f};

#define STAGE_KV(BUF, KV0) do { \
    _Pragma("unroll") \
    for (int i=0;i<2;i++){ \
      int c = tid + i*256; \
      int sj = c >> 3, slot = c & 7; \
      gload16(kp + base + ((size_t)((KV0)+sj) << 10) + colh + ((slot ^ (sj & 7)) << 3), \
              &Ks[BUF][(i*256 + w*64) * 8]); \
    } \
    _Pragma("unroll") \
    for (int i=0;i<2;i++){ \
      int c = tid + i*256; \
      int d = c >> 3, slot = c & 7; \
      gload16(vtg + vbase + ((size_t)d << 10) + (KV0) + ((slot ^ (d & 7)) << 3), \
              &Vs[BUF][(i*256 + w*64) * 8]); \
    } \
  } while(0)

  STAGE_KV(0, 0);
  __syncthreads();

  int cur = 0;
  for (int t = 0; t < 16; t++){
    if (t < 15) STAGE_KV(cur ^ 1, (t+1) << 6);
    const u16* ksb = Ks[cur];
    const u16* vsb = Vs[cur];

    f32x4 e2[4];
#pragma unroll
    for (int sjf=0;sjf<4;sjf++){
      e2[sjf] = (f32x4){0.f,0.f,0.f,0.f};
      int sj = sjf*16 + s;
      bf16x8 kf0 = *(const bf16x8*)&ksb[sj*64 + ((g ^ (s & 7)) << 3)];
      e2[sjf] = __builtin_amdgcn_mfma_f32_16x16x32_bf16(kf0, qf0, e2[sjf], 0, 0, 0);
      bf16x8 kf1 = *(const bf16x8*)&ksb[sj*64 + (((4+g) ^ (s & 7)) << 3)];
      e2[sjf] = __builtin_amdgcn_mfma_f32_16x16x32_bf16(kf1, qf1, e2[sjf], 0, 0, 0);
    }
    float rm = fmaxf(fmaxf(e2[0][0], e2[0][1]), e2[0][2]);
    rm = fmaxf(fmaxf(rm, e2[0][3]), e2[1][0]);
    rm = fmaxf(fmaxf(rm, e2[1][1]), e2[1][2]);
    rm = fmaxf(fmaxf(rm, e2[1][3]), e2[2][0]);
    rm = fmaxf(fmaxf(rm, e2[2][1]), e2[2][2]);
    rm = fmaxf(fmaxf(rm, e2[2][3]), e2[3][0]);
    rm = fmaxf(fmaxf(rm, e2[3][1]), e2[3][2]);
    rm = fmaxf(rm, e2[3][3]);
    rm = fmaxf(rm, __shfl_xor(rm, 16, 64));
    rm = fmaxf(rm, __shfl_xor(rm, 32, 64));
    if (!__all(rm <= mrun + 177.0f)){
      float nm = fmaxf(mrun, rm);
      float alpha = __builtin_amdgcn_exp2f((mrun - nm) * KL);
      mrun = nm;
      lsum *= alpha;
      float ac[4];
#pragma unroll
      for (int r=0;r<4;r++) ac[r] = __shfl(alpha, g*4 + r, 64);
#pragma unroll
      for (int d=0; d<4; d++)
#pragma unroll
        for (int r=0;r<4;r++) of[d][r] *= ac[r];
    }

    const float mk = mrun * KL;
#pragma unroll
    for (int sjf=0;sjf<4;sjf++){
      float p0 = __builtin_amdgcn_exp2f(e2[sjf][0]*KL - mk);
      float p1 = __builtin_amdgcn_exp2f(e2[sjf][1]*KL - mk);
      float p2 = __builtin_amdgcn_exp2f(e2[sjf][2]*KL - mk);
      float p3 = __builtin_amdgcn_exp2f(e2[sjf][3]*KL - mk);
      lsum += (p0 + p1) + (p2 + p3);
      uint2 pk; pk.x = cvtpk(p0, p1); pk.y = cvtpk(p2, p3);
      int phys = (8*sjf + 2*g) ^ sx2;
      *reinterpret_cast<uint2*>(&PsW[(s << 5) + phys]) = pk;
    }
    union { u32 u[4]; bf16x8 v; } pa0, pa1;
    {
      uint2 r0 = *reinterpret_cast<const uint2*>(&PsW[(s << 5) + ((4*g    ) ^ sx2)]);
      uint2 r1 = *reinterpret_cast<const uint2*>(&PsW[(s << 5) + ((4*g + 2) ^ sx2)]);
      pa0.u[0] = r0.x; pa0.u[1] = r0.y; pa0.u[2] = r1.x; pa0.u[3] = r1.y;
      uint2 r2 = *reinterpret_cast<const uint2*>(&PsW[(s << 5) + ((16 + 4*g    ) ^ sx2)]);
      uint2 r3 = *reinterpret_cast<const uint2*>(&PsW[(s << 5) + ((16 + 4*g + 2) ^ sx2)]);
      pa1.u[0] = r2.x; pa1.u[1] = r2.y; pa1.u[2] = r3.x; pa1.u[3] = r3.y;
    }
#pragma unroll
    for (int df=0; df<4; df++){
      int d = df*16 + s;
      bf16x8 v0 = *(const bf16x8*)&vsb[d*64 + ((g ^ (s & 7)) << 3)];
      bf16x8 v1 = *(const bf16x8*)&vsb[d*64 + (((4+g) ^ (s & 7)) << 3)];
      of[df] = __builtin_amdgcn_mfma_f32_16x16x32_bf16(pa0.v, v0, of[df], 0, 0, 0);
      of[df] = __builtin_amdgcn_mfma_f32_16x16x32_bf16(pa1.v, v1, of[df], 0, 0, 0);
    }
    __syncthreads();
    cur ^= 1;
  }
#undef STAGE_KV

  lsum += __shfl_xor(lsum, 16, 64);
  lsum += __shfl_xor(lsum, 32, 64);
  float inv = 1.0f / lsum;
  float ic[4];
#pragma unroll
  for (int r=0;r<4;r++) ic[r] = __shfl(inv, g*4 + r, 64);
#pragma unroll
  for (int df=0; df<4; df++){
#pragma unroll
    for (int r=0;r<4;r++){
      size_t row = (size_t)(q0 + w*16 + g*4 + r);
      size_t idx = base + (row << 10) + colh + df*16 + s;
      float o = of[df][r] * ic[r];
      float rg = bf2f(rp[idx]);
      gated[idx] = f2bf(o * rg);
    }
  }
}

extern "C" void kernel_launch(void* const* d_in, const int* in_sizes, int n_in,
                              void* d_out, int out_size, void* d_ws, size_t ws_size,
                              hipStream_t stream){
  (void)in_sizes; (void)n_in; (void)out_size; (void)ws_size;
  const float* value = (const float*)d_in[0];
  const float* key   = (const float*)d_in[1];
  const float* query = (const float*)d_in[2];
  const float* Wq = (const float*)d_in[3];  const float* bq = (const float*)d_in[4];
  const float* Wk = (const float*)d_in[5];  const float* bk = (const float*)d_in[6];
  const float* Wv = (const float*)d_in[7];  const float* bv = (const float*)d_in[8];
  const float* Wr = (const float*)d_in[9];  const float* br = (const float*)d_in[10];
  const float* Wo = (const float*)d_in[11]; const float* bo = (const float*)d_in[12];

  char* ws = (char*)d_ws;
  const size_t MB = (size_t)1 << 20;
  u16* qb   = (u16*)(ws + 0*MB);
  u16* kb   = (u16*)(ws + 16*MB);
  u16* vb   = (u16*)(ws + 32*MB);
  u16* wall = (u16*)(ws + 48*MB);    // 8 MB: [Wq^T | Wr^T | Wk^T | Wv^T] bf16 [4096][1024]
  u16* wot  = (u16*)(ws + 56*MB);
  u16* qpj  = (u16*)(ws + 58*MB);
  u16* kpj  = (u16*)(ws + 74*MB);
  u16* vtg  = (u16*)(ws + 90*MB);    // V projection, pre-transposed [(b*16+h)*64+d][sq]
  u16* rpj  = (u16*)(ws + 106*MB);
  u16* gat  = qb;

  (void)hipFuncSetAttribute(reinterpret_cast<const void*>(&k_proj8),
                            hipFuncAttributeMaxDynamicSharedMemorySize, 131072);

  k_cvt_act<<<dim3(4096, 3), 256, 0, stream>>>(value, key, query, vb, kb, qb);
  k_cvt_wt<<<dim3(32, 32, 5), dim3(32, 8), 0, stream>>>(Wq, Wr, Wk, Wv, Wo, wall, wot);
  k_proj8<<<dim3(32, 16), 512, 131072, stream>>>(qb, kb, vb, wall, bq, br, bk, bv,
                                                 qpj, rpj, kpj, vtg);
  k_attn<<<2048, 256, 0, stream>>>(qpj, kpj, vtg, rpj, gat);
  k_gemm_out<<<dim3(64, 8), 256, 0, stream>>>(gat, wot, bo, (float*)d_out);
}